// Round 8
// baseline (249.595 us; speedup 1.0000x reference)
//
#include <hip/hip_runtime.h>

#define BB 8192
#define TT 2048
// sweep1: chunks of 32 steps, 16-step h warmup; 1 (h, A, B) window per chunk
#define NC1 64
#define CL1 32
#define WU  16
// sweep2: 32-step windows, 1 per lane; one wave = one row
#define NW  64   // windows per row
#define CL2 32
#define LPAD 36  // padded LDS row stride (words) per window

__device__ __forceinline__ float sig2(float z) {
    return __builtin_amdgcn_rcpf(1.f + __builtin_amdgcn_exp2f(z));
}
__device__ __forceinline__ float sgpr(float v) {
    return __builtin_bit_cast(float, __builtin_amdgcn_readfirstlane(__builtin_bit_cast(int, v)));
}
__device__ __forceinline__ void ld16(float* d, const float* p) {
    *(float4*)(d)      = *(const float4*)(p);
    *(float4*)(d + 4)  = *(const float4*)(p + 4);
    *(float4*)(d + 8)  = *(const float4*)(p + 8);
    *(float4*)(d + 12) = *(const float4*)(p + 12);
}

#define LOAD_WHH()                                                                  \
    const float wh00=sgpr(Whh[0]*NL2E),  wh01=sgpr(Whh[1]*NL2E),                    \
                wh02=sgpr(Whh[2]*NL2E),  wh03=sgpr(Whh[3]*NL2E),                    \
                wh10=sgpr(Whh[4]*NL2E),  wh11=sgpr(Whh[5]*NL2E),                    \
                wh12=sgpr(Whh[6]*NL2E),  wh13=sgpr(Whh[7]*NL2E),                    \
                wh20=sgpr(Whh[8]*NL2E),  wh21=sgpr(Whh[9]*NL2E),                    \
                wh22=sgpr(Whh[10]*NL2E), wh23=sgpr(Whh[11]*NL2E),                   \
                wh30=sgpr(Whh[12]*NL2E), wh31=sgpr(Whh[13]*NL2E),                   \
                wh32=sgpr(Whh[14]*NL2E), wh33=sgpr(Whh[15]*NL2E);                   \
    const float wx0=sgpr(Wxh[0]*NL2E), wx1=sgpr(Wxh[1]*NL2E),                       \
                wx2=sgpr(Wxh[2]*NL2E), wx3=sgpr(Wxh[3]*NL2E);                       \
    const float bh0=sgpr(bh[0]*NL2E), bh1=sgpr(bh[1]*NL2E),                         \
                bh2=sgpr(bh[2]*NL2E), bh3=sgpr(bh[3]*NL2E);

#define HSTEP(xs)                                                                   \
    {                                                                               \
        float z0 = fmaf(h3,wh30,fmaf(h2,wh20,fmaf(h1,wh10,fmaf(h0,wh00,fmaf(xs,wx0,bh0))))); \
        float z1 = fmaf(h3,wh31,fmaf(h2,wh21,fmaf(h1,wh11,fmaf(h0,wh01,fmaf(xs,wx1,bh1))))); \
        float z2 = fmaf(h3,wh32,fmaf(h2,wh22,fmaf(h1,wh12,fmaf(h0,wh02,fmaf(xs,wx2,bh2))))); \
        float z3 = fmaf(h3,wh33,fmaf(h2,wh23,fmaf(h1,wh13,fmaf(h0,wh03,fmaf(xs,wx3,bh3))))); \
        h0 = sig2(z0); h1 = sig2(z1); h2 = sig2(z2); h3 = sig2(z3);                 \
    }
#define HSTEPx16(buf)                                                               \
    HSTEP(buf[0])  HSTEP(buf[1])  HSTEP(buf[2])  HSTEP(buf[3])                      \
    HSTEP(buf[4])  HSTEP(buf[5])  HSTEP(buf[6])  HSTEP(buf[7])                      \
    HSTEP(buf[8])  HSTEP(buf[9])  HSTEP(buf[10]) HSTEP(buf[11])                     \
    HSTEP(buf[12]) HSTEP(buf[13]) HSTEP(buf[14]) HSTEP(buf[15])

// ---- sweep 1: lane = (row b, 32-step chunk c1); h-snapshot + (A,B) per chunk ----
__global__ __launch_bounds__(256, 6) void bkt_sweep1(
    const float* __restrict__ x, const float* __restrict__ Wxh,
    const float* __restrict__ Whh, const float* __restrict__ bh,
    const float* __restrict__ Wy, const float* __restrict__ by,
    float2* __restrict__ AB2, float4* __restrict__ hstart4)
{
    const int tid = blockIdx.x * 256 + threadIdx.x;   // = b*64 + c1
    const int c1 = tid & (NC1 - 1);
    const int b  = tid >> 6;
    const float NL2E = -1.44269504088896340736f;

    LOAD_WHH();
    const float wl0=sgpr(Wy[0]*NL2E),  wl1=sgpr(Wy[4]*NL2E),
                wl2=sgpr(Wy[8]*NL2E),  wl3=sgpr(Wy[12]*NL2E);
    const float wf0=sgpr(Wy[1]*NL2E),  wf1=sgpr(Wy[5]*NL2E),
                wf2=sgpr(Wy[9]*NL2E),  wf3=sgpr(Wy[13]*NL2E);
    const float byl=sgpr(by[0]*NL2E), byf=sgpr(by[1]*NL2E);

    const float* xr = x + (size_t)b * TT;
    const int t0 = c1 * CL1;

    float xa[16], xn[16];
    ld16(xa, xr + (c1 ? t0 - WU : 0));       // warmup block
    ld16(xn, xr + t0);                       // first half of main window

    float h0=0.f, h1=0.f, h2=0.f, h3=0.f;
    HSTEPx16(xa)
    if (c1 == 0) { h0 = h1 = h2 = h3 = 0.f; }   // exact start for first chunk

    const float4 hs0 = make_float4(h0, h1, h2, h3);   // h entering window c1
    ld16(xa, xr + t0 + 16);

    float Aacc = 1.f, Bacc = 0.f;
#define S1(buf, s)                                                                  \
    {                                                                               \
        float zl = fmaf(h3,wl3,fmaf(h2,wl2,fmaf(h1,wl1,fmaf(h0,wl0,byl))));         \
        float zf = fmaf(h3,wf3,fmaf(h2,wf2,fmaf(h1,wf1,fmaf(h0,wf0,byf))));         \
        float pl = sig2(zl), pf = sig2(zf);                                         \
        float a = (1.f - pf) - pl;                                                  \
        Bacc = fmaf(a, Bacc, pl);                                                   \
        Aacc *= a;                                                                  \
        HSTEP(buf[s])                                                               \
    }
#define S1x16(buf)                                                                  \
    S1(buf,0)  S1(buf,1)  S1(buf,2)  S1(buf,3)  S1(buf,4)  S1(buf,5)  S1(buf,6)  S1(buf,7) \
    S1(buf,8)  S1(buf,9)  S1(buf,10) S1(buf,11) S1(buf,12) S1(buf,13) S1(buf,14) S1(buf,15)

    S1x16(xn)                                           // t0 .. t0+15
    S1x16(xa)                                           // t0+16 .. t0+31
#undef S1x16
#undef S1

    // contiguous per-instruction stores: 16B/lane and 8B/lane, lanes adjacent
    hstart4[(size_t)b * NW + c1] = hs0;
    AB2[(size_t)b * NW + c1] = make_float2(Aacc, Bacc);
}

// ---- middle pass: exact window-start latents ----
__global__ __launch_bounds__(256) void bkt_mid(
    const float2* __restrict__ AB2, const float* __restrict__ prior,
    float* __restrict__ latstart)
{
    const int b = blockIdx.x * 256 + threadIdx.x;   // 8192 threads
    float L = prior[0];
    const float2* ab = AB2 + (size_t)b * NW;
    float* Lr = latstart + (size_t)b * NW;
#pragma unroll
    for (int w = 0; w < NW; ++w) {
        Lr[w] = L;
        const float2 v = ab[w];
        L = fmaf(v.x, L, v.y);
    }
}

// ---- sweep 2: lane = 32-step window; one wave = one row; LDS-transposed stores ----
__global__ __launch_bounds__(256, 4) void bkt_sweep2(
    const float* __restrict__ x, const float* __restrict__ y,
    const float* __restrict__ Wxh, const float* __restrict__ Whh,
    const float* __restrict__ bh, const float* __restrict__ Wy,
    const float* __restrict__ by,
    const float4* __restrict__ hstart4, const float* __restrict__ latstart,
    float* __restrict__ corrects, float* __restrict__ latents,
    float* __restrict__ partials)
{
    __shared__ float lds[4 * 64 * LPAD];               // 36.9 KB: one slice per wave
    const int tid  = blockIdx.x * 256 + threadIdx.x;   // = b*64 + c
    const int lane = threadIdx.x & 63;                 // = window c
    const int b    = tid >> 6;                         // row (uniform per wave)
    float* wls = &lds[(threadIdx.x >> 6) * 64 * LPAD];
    const float NL2E = -1.44269504088896340736f;

    LOAD_WHH();
    const float wy00=sgpr(Wy[0]*NL2E),  wy01=sgpr(Wy[1]*NL2E),
                wy02=sgpr(Wy[2]*NL2E),  wy03=sgpr(Wy[3]*NL2E),
                wy10=sgpr(Wy[4]*NL2E),  wy11=sgpr(Wy[5]*NL2E),
                wy12=sgpr(Wy[6]*NL2E),  wy13=sgpr(Wy[7]*NL2E),
                wy20=sgpr(Wy[8]*NL2E),  wy21=sgpr(Wy[9]*NL2E),
                wy22=sgpr(Wy[10]*NL2E), wy23=sgpr(Wy[11]*NL2E),
                wy30=sgpr(Wy[12]*NL2E), wy31=sgpr(Wy[13]*NL2E),
                wy32=sgpr(Wy[14]*NL2E), wy33=sgpr(Wy[15]*NL2E);
    const float by0=sgpr(by[0]*NL2E), by1=sgpr(by[1]*NL2E),
                by2=sgpr(by[2]*NL2E), by3=sgpr(by[3]*NL2E);

    const int t0 = lane * CL2;
    const float* xr = x + (size_t)b * TT + t0;
    const float* yr = y + (size_t)b * TT + t0;
    float* crow = corrects + (size_t)b * TT;
    float* lrow = latents  + (size_t)b * TT;

    const float4 hv = hstart4[(size_t)b * NW + lane];
    float h0 = hv.x, h1 = hv.y, h2 = hv.z, h3 = hv.w;
    float lat = latstart[(size_t)b * NW + lane];
    float lacc = 0.f;

    float xb[16], yb[16], cb[32], lb[32];

#define S2(s, o)                                                                    \
    {                                                                               \
        float zl = fmaf(h3,wy30,fmaf(h2,wy20,fmaf(h1,wy10,fmaf(h0,wy00,by0))));     \
        float zf = fmaf(h3,wy31,fmaf(h2,wy21,fmaf(h1,wy11,fmaf(h0,wy01,by1))));     \
        float zg = fmaf(h3,wy32,fmaf(h2,wy22,fmaf(h1,wy12,fmaf(h0,wy02,by2))));     \
        float zs = fmaf(h3,wy33,fmaf(h2,wy23,fmaf(h1,wy13,fmaf(h0,wy03,by3))));     \
        float pl = sig2(zl), pf = sig2(zf), pg = sig2(zg), ps = sig2(zs);           \
        float correct = fmaf(lat, (1.f - ps) - pg, pg);                             \
        float nl      = fmaf(lat, (1.f - pf) - pl, pl);                             \
        float cc  = fminf(fmaxf(correct, 1e-7f), 1.f - 1e-7f);                      \
        float arg = fmaf(yb[s], fmaf(2.f, cc, -1.f), 1.f - cc);                     \
        lacc += __builtin_amdgcn_logf(arg);                                         \
        cb[(o)+(s)] = correct; lb[(o)+(s)] = nl; lat = nl;                          \
        HSTEP(xb[s])                                                                \
    }
#define S2x16(o)                                                                    \
    S2(0,o)  S2(1,o)  S2(2,o)  S2(3,o)  S2(4,o)  S2(5,o)  S2(6,o)  S2(7,o)          \
    S2(8,o)  S2(9,o)  S2(10,o) S2(11,o) S2(12,o) S2(13,o) S2(14,o) S2(15,o)

    ld16(xb, xr);      ld16(yb, yr);
    S2x16(0)
    ld16(xb, xr + 16); ld16(yb, yr + 16);
    S2x16(16)
#undef S2x16
#undef S2

    // ---- transpose-store corrects: each global store instr = contiguous 1 KB ----
#pragma unroll
    for (int k = 0; k < 8; ++k)
        *(float4*)&wls[lane * LPAD + 4 * k] = *(float4*)&cb[4 * k];
    __syncthreads();
#pragma unroll
    for (int j = 0; j < 8; ++j) {
        float4 v = *(float4*)&wls[(8 * j + (lane >> 3)) * LPAD + 4 * (lane & 7)];
        *(float4*)(crow + j * 256 + 4 * lane) = v;
    }
    __syncthreads();
    // ---- transpose-store latents ----
#pragma unroll
    for (int k = 0; k < 8; ++k)
        *(float4*)&wls[lane * LPAD + 4 * k] = *(float4*)&lb[4 * k];
    __syncthreads();
#pragma unroll
    for (int j = 0; j < 8; ++j) {
        float4 v = *(float4*)&wls[(8 * j + (lane >> 3)) * LPAD + 4 * (lane & 7)];
        *(float4*)(lrow + j * 256 + 4 * lane) = v;
    }

#pragma unroll
    for (int off = 32; off; off >>= 1) lacc += __shfl_down(lacc, off);
    if ((threadIdx.x & 63) == 0) partials[tid >> 6] = lacc;
}

__global__ __launch_bounds__(256) void bkt_loss(const float* __restrict__ partials, int n,
                                                float* __restrict__ out_loss)
{
    __shared__ double sd[4];
    double s = 0.0;
    for (int i = threadIdx.x; i < n; i += 256) s += (double)partials[i];
#pragma unroll
    for (int off = 32; off; off >>= 1) s += __shfl_down(s, off);
    if ((threadIdx.x & 63) == 0) sd[threadIdx.x >> 6] = s;
    __syncthreads();
    if (threadIdx.x == 0) {
        double t = sd[0] + sd[1] + sd[2] + sd[3];
        *out_loss = (float)(-t * 0.69314718055994530942 / ((double)BB * (double)TT));
    }
}

extern "C" void kernel_launch(void* const* d_in, const int* in_sizes, int n_in,
                              void* d_out, int out_size, void* d_ws, size_t ws_size,
                              hipStream_t stream)
{
    const float* x     = (const float*)d_in[0];
    const float* y     = (const float*)d_in[1];
    const float* Wxh   = (const float*)d_in[2];
    const float* Whh   = (const float*)d_in[3];
    const float* bh    = (const float*)d_in[4];
    const float* Wy    = (const float*)d_in[5];
    const float* by    = (const float*)d_in[6];
    const float* prior = (const float*)d_in[7];

    float* out      = (float*)d_out;
    float* corrects = out;
    float* latents  = out + (size_t)BB * TT;
    float* lossp    = out + (size_t)2 * BB * TT;

    // workspace layout (floats): hstart4 first for 16B alignment
    float*  ws       = (float*)d_ws;
    float4* hstart4  = (float4*)ws;                          // BB*NW float4 (8 MB)
    float2* AB2      = (float2*)(ws + (size_t)BB * NW * 4);  // BB*NW float2 (4 MB)
    float*  latstart = ws + (size_t)BB * NW * 6;             // BB*NW (2 MB)
    float*  partials = latstart + (size_t)BB * NW;           // 8192 floats

    const int thr = BB * NW;                                 // 524288 lanes each sweep

    bkt_sweep1<<<thr / 256, 256, 0, stream>>>(x, Wxh, Whh, bh, Wy, by, AB2, hstart4);
    bkt_mid<<<BB / 256, 256, 0, stream>>>(AB2, prior, latstart);
    bkt_sweep2<<<thr / 256, 256, 0, stream>>>(x, y, Wxh, Whh, bh, Wy, by,
                                              hstart4, latstart,
                                              corrects, latents, partials);
    bkt_loss<<<1, 256, 0, stream>>>(partials, thr / 64, lossp);
}

// Round 9
// 154.135 us; speedup vs baseline: 1.6193x; 1.6193x over previous
//
#include <hip/hip_runtime.h>

#define BB 8192
#define TT 2048
// sweep1: chunks of 32 steps, 16-step h warmup; 1 (h, A, B) window per chunk
#define NC1 64
#define CL1 32
#define WU  16
// sweep2: 32-step windows, 1 per lane; one wave = one row
#define NW  64   // windows per row
#define CL2 32
#define LST 33   // LDS stride per window (words): odd -> conflict-free b32 ops

__device__ __forceinline__ float sig2(float z) {
    return __builtin_amdgcn_rcpf(1.f + __builtin_amdgcn_exp2f(z));
}
__device__ __forceinline__ float sgpr(float v) {
    return __builtin_bit_cast(float, __builtin_amdgcn_readfirstlane(__builtin_bit_cast(int, v)));
}
__device__ __forceinline__ void ld16(float* d, const float* p) {
    *(float4*)(d)      = *(const float4*)(p);
    *(float4*)(d + 4)  = *(const float4*)(p + 4);
    *(float4*)(d + 8)  = *(const float4*)(p + 8);
    *(float4*)(d + 12) = *(const float4*)(p + 12);
}

#define LOAD_WHH()                                                                  \
    const float wh00=sgpr(Whh[0]*NL2E),  wh01=sgpr(Whh[1]*NL2E),                    \
                wh02=sgpr(Whh[2]*NL2E),  wh03=sgpr(Whh[3]*NL2E),                    \
                wh10=sgpr(Whh[4]*NL2E),  wh11=sgpr(Whh[5]*NL2E),                    \
                wh12=sgpr(Whh[6]*NL2E),  wh13=sgpr(Whh[7]*NL2E),                    \
                wh20=sgpr(Whh[8]*NL2E),  wh21=sgpr(Whh[9]*NL2E),                    \
                wh22=sgpr(Whh[10]*NL2E), wh23=sgpr(Whh[11]*NL2E),                   \
                wh30=sgpr(Whh[12]*NL2E), wh31=sgpr(Whh[13]*NL2E),                   \
                wh32=sgpr(Whh[14]*NL2E), wh33=sgpr(Whh[15]*NL2E);                   \
    const float wx0=sgpr(Wxh[0]*NL2E), wx1=sgpr(Wxh[1]*NL2E),                       \
                wx2=sgpr(Wxh[2]*NL2E), wx3=sgpr(Wxh[3]*NL2E);                       \
    const float bh0=sgpr(bh[0]*NL2E), bh1=sgpr(bh[1]*NL2E),                         \
                bh2=sgpr(bh[2]*NL2E), bh3=sgpr(bh[3]*NL2E);

#define HSTEP(xs)                                                                   \
    {                                                                               \
        float z0 = fmaf(h3,wh30,fmaf(h2,wh20,fmaf(h1,wh10,fmaf(h0,wh00,fmaf(xs,wx0,bh0))))); \
        float z1 = fmaf(h3,wh31,fmaf(h2,wh21,fmaf(h1,wh11,fmaf(h0,wh01,fmaf(xs,wx1,bh1))))); \
        float z2 = fmaf(h3,wh32,fmaf(h2,wh22,fmaf(h1,wh12,fmaf(h0,wh02,fmaf(xs,wx2,bh2))))); \
        float z3 = fmaf(h3,wh33,fmaf(h2,wh23,fmaf(h1,wh13,fmaf(h0,wh03,fmaf(xs,wx3,bh3))))); \
        h0 = sig2(z0); h1 = sig2(z1); h2 = sig2(z2); h3 = sig2(z3);                 \
    }
#define HSTEPx16(buf)                                                               \
    HSTEP(buf[0])  HSTEP(buf[1])  HSTEP(buf[2])  HSTEP(buf[3])                      \
    HSTEP(buf[4])  HSTEP(buf[5])  HSTEP(buf[6])  HSTEP(buf[7])                      \
    HSTEP(buf[8])  HSTEP(buf[9])  HSTEP(buf[10]) HSTEP(buf[11])                     \
    HSTEP(buf[12]) HSTEP(buf[13]) HSTEP(buf[14]) HSTEP(buf[15])

// ---- sweep 1: lane = (row b, 32-step chunk c1); h-snapshot + (A,B) per chunk ----
__global__ __launch_bounds__(256, 6) void bkt_sweep1(
    const float* __restrict__ x, const float* __restrict__ Wxh,
    const float* __restrict__ Whh, const float* __restrict__ bh,
    const float* __restrict__ Wy, const float* __restrict__ by,
    float2* __restrict__ AB2, float4* __restrict__ hstart4)
{
    const int tid = blockIdx.x * 256 + threadIdx.x;   // = b*64 + c1
    const int c1 = tid & (NC1 - 1);
    const int b  = tid >> 6;
    const float NL2E = -1.44269504088896340736f;

    LOAD_WHH();
    const float wl0=sgpr(Wy[0]*NL2E),  wl1=sgpr(Wy[4]*NL2E),
                wl2=sgpr(Wy[8]*NL2E),  wl3=sgpr(Wy[12]*NL2E);
    const float wf0=sgpr(Wy[1]*NL2E),  wf1=sgpr(Wy[5]*NL2E),
                wf2=sgpr(Wy[9]*NL2E),  wf3=sgpr(Wy[13]*NL2E);
    const float byl=sgpr(by[0]*NL2E), byf=sgpr(by[1]*NL2E);

    const float* xr = x + (size_t)b * TT;
    const int t0 = c1 * CL1;

    float xa[16], xn[16];
    ld16(xa, xr + (c1 ? t0 - WU : 0));       // warmup block
    ld16(xn, xr + t0);                       // first half of main window

    float h0=0.f, h1=0.f, h2=0.f, h3=0.f;
    HSTEPx16(xa)
    if (c1 == 0) { h0 = h1 = h2 = h3 = 0.f; }   // exact start for first chunk

    const float4 hs0 = make_float4(h0, h1, h2, h3);   // h entering window c1
    ld16(xa, xr + t0 + 16);

    float Aacc = 1.f, Bacc = 0.f;
#define S1(buf, s)                                                                  \
    {                                                                               \
        float zl = fmaf(h3,wl3,fmaf(h2,wl2,fmaf(h1,wl1,fmaf(h0,wl0,byl))));         \
        float zf = fmaf(h3,wf3,fmaf(h2,wf2,fmaf(h1,wf1,fmaf(h0,wf0,byf))));         \
        float pl = sig2(zl), pf = sig2(zf);                                         \
        float a = (1.f - pf) - pl;                                                  \
        Bacc = fmaf(a, Bacc, pl);                                                   \
        Aacc *= a;                                                                  \
        HSTEP(buf[s])                                                               \
    }
#define S1x16(buf)                                                                  \
    S1(buf,0)  S1(buf,1)  S1(buf,2)  S1(buf,3)  S1(buf,4)  S1(buf,5)  S1(buf,6)  S1(buf,7) \
    S1(buf,8)  S1(buf,9)  S1(buf,10) S1(buf,11) S1(buf,12) S1(buf,13) S1(buf,14) S1(buf,15)

    S1x16(xn)                                           // t0 .. t0+15
    S1x16(xa)                                           // t0+16 .. t0+31
#undef S1x16
#undef S1

    hstart4[(size_t)b * NW + c1] = hs0;
    AB2[(size_t)b * NW + c1] = make_float2(Aacc, Bacc);
}

// ---- middle pass: exact window-start latents ----
__global__ __launch_bounds__(256) void bkt_mid(
    const float2* __restrict__ AB2, const float* __restrict__ prior,
    float* __restrict__ latstart)
{
    const int b = blockIdx.x * 256 + threadIdx.x;   // 8192 threads
    float L = prior[0];
    const float2* ab = AB2 + (size_t)b * NW;
    float* Lr = latstart + (size_t)b * NW;
#pragma unroll
    for (int w = 0; w < NW; ++w) {
        Lr[w] = L;
        const float2 v = ab[w];
        L = fmaf(v.x, L, v.y);
    }
}

// ---- sweep 2: lane = 32-step window; one wave = one row; streamed LDS transpose ----
__global__ __launch_bounds__(256, 4) void bkt_sweep2(
    const float* __restrict__ x, const float* __restrict__ y,
    const float* __restrict__ Wxh, const float* __restrict__ Whh,
    const float* __restrict__ bh, const float* __restrict__ Wy,
    const float* __restrict__ by,
    const float4* __restrict__ hstart4, const float* __restrict__ latstart,
    float* __restrict__ corrects, float* __restrict__ latents,
    float* __restrict__ partials)
{
    __shared__ float lds[4 * NW * LST];                // 33.8 KB: one slice per wave
    const int tid  = blockIdx.x * 256 + threadIdx.x;   // = b*64 + c
    const int lane = threadIdx.x & 63;                 // = window c
    const int b    = tid >> 6;                         // row (uniform per wave)
    float* wls = &lds[(threadIdx.x >> 6) * NW * LST];
    const int w33 = lane * LST;                        // this lane's LDS row
    const float NL2E = -1.44269504088896340736f;

    LOAD_WHH();
    const float wy00=sgpr(Wy[0]*NL2E),  wy01=sgpr(Wy[1]*NL2E),
                wy02=sgpr(Wy[2]*NL2E),  wy03=sgpr(Wy[3]*NL2E),
                wy10=sgpr(Wy[4]*NL2E),  wy11=sgpr(Wy[5]*NL2E),
                wy12=sgpr(Wy[6]*NL2E),  wy13=sgpr(Wy[7]*NL2E),
                wy20=sgpr(Wy[8]*NL2E),  wy21=sgpr(Wy[9]*NL2E),
                wy22=sgpr(Wy[10]*NL2E), wy23=sgpr(Wy[11]*NL2E),
                wy30=sgpr(Wy[12]*NL2E), wy31=sgpr(Wy[13]*NL2E),
                wy32=sgpr(Wy[14]*NL2E), wy33=sgpr(Wy[15]*NL2E);
    const float by0=sgpr(by[0]*NL2E), by1=sgpr(by[1]*NL2E),
                by2=sgpr(by[2]*NL2E), by3=sgpr(by[3]*NL2E);

    const int t0 = lane * CL2;
    const float* xr = x + (size_t)b * TT + t0;
    const float* yr = y + (size_t)b * TT + t0;
    float* crow = corrects + (size_t)b * TT;
    float* lrow = latents  + (size_t)b * TT;

    const float4 hv = hstart4[(size_t)b * NW + lane];
    float h0 = hv.x, h1 = hv.y, h2 = hv.z, h3 = hv.w;
    float lat = latstart[(size_t)b * NW + lane];
    float lacc = 0.f;

    float xb[16], yb[16], lb[32];

    // stream correct -> LDS (ds_write_b32, stride-33 = conflict-free); latents in regs
#define S2(s, o)                                                                    \
    {                                                                               \
        float zl = fmaf(h3,wy30,fmaf(h2,wy20,fmaf(h1,wy10,fmaf(h0,wy00,by0))));     \
        float zf = fmaf(h3,wy31,fmaf(h2,wy21,fmaf(h1,wy11,fmaf(h0,wy01,by1))));     \
        float zg = fmaf(h3,wy32,fmaf(h2,wy22,fmaf(h1,wy12,fmaf(h0,wy02,by2))));     \
        float zs = fmaf(h3,wy33,fmaf(h2,wy23,fmaf(h1,wy13,fmaf(h0,wy03,by3))));     \
        float pl = sig2(zl), pf = sig2(zf), pg = sig2(zg), ps = sig2(zs);           \
        float correct = fmaf(lat, (1.f - ps) - pg, pg);                             \
        float nl      = fmaf(lat, (1.f - pf) - pl, pl);                             \
        float cc  = fminf(fmaxf(correct, 1e-7f), 1.f - 1e-7f);                      \
        float arg = fmaf(yb[s], fmaf(2.f, cc, -1.f), 1.f - cc);                     \
        lacc += __builtin_amdgcn_logf(arg);                                         \
        wls[w33 + (o) + (s)] = correct;                                             \
        lb[(o)+(s)] = nl; lat = nl;                                                 \
        HSTEP(xb[s])                                                                \
    }
#define S2x16(o)                                                                    \
    S2(0,o)  S2(1,o)  S2(2,o)  S2(3,o)  S2(4,o)  S2(5,o)  S2(6,o)  S2(7,o)          \
    S2(8,o)  S2(9,o)  S2(10,o) S2(11,o) S2(12,o) S2(13,o) S2(14,o) S2(15,o)

    ld16(xb, xr);      ld16(yb, yr);
    S2x16(0)
    ld16(xb, xr + 16); ld16(yb, yr + 16);
    S2x16(16)
#undef S2x16
#undef S2

    // ---- corrects: transposed readback; each global store instr = contiguous 1 KB ----
#pragma unroll
    for (int j = 0; j < 8; ++j) {
        const int base = (8 * j + (lane >> 3)) * LST + 4 * (lane & 7);
        float4 v = make_float4(wls[base], wls[base + 1], wls[base + 2], wls[base + 3]);
        *(float4*)(crow + j * 256 + 4 * lane) = v;
    }
    // ---- latents: dump regs to the same slice, then transposed readback ----
#pragma unroll
    for (int s = 0; s < 32; ++s) wls[w33 + s] = lb[s];
#pragma unroll
    for (int j = 0; j < 8; ++j) {
        const int base = (8 * j + (lane >> 3)) * LST + 4 * (lane & 7);
        float4 v = make_float4(wls[base], wls[base + 1], wls[base + 2], wls[base + 3]);
        *(float4*)(lrow + j * 256 + 4 * lane) = v;
    }

#pragma unroll
    for (int off = 32; off; off >>= 1) lacc += __shfl_down(lacc, off);
    if ((threadIdx.x & 63) == 0) partials[tid >> 6] = lacc;
}

__global__ __launch_bounds__(256) void bkt_loss(const float* __restrict__ partials, int n,
                                                float* __restrict__ out_loss)
{
    __shared__ double sd[4];
    double s = 0.0;
    for (int i = threadIdx.x; i < n; i += 256) s += (double)partials[i];
#pragma unroll
    for (int off = 32; off; off >>= 1) s += __shfl_down(s, off);
    if ((threadIdx.x & 63) == 0) sd[threadIdx.x >> 6] = s;
    __syncthreads();
    if (threadIdx.x == 0) {
        double t = sd[0] + sd[1] + sd[2] + sd[3];
        *out_loss = (float)(-t * 0.69314718055994530942 / ((double)BB * (double)TT));
    }
}

extern "C" void kernel_launch(void* const* d_in, const int* in_sizes, int n_in,
                              void* d_out, int out_size, void* d_ws, size_t ws_size,
                              hipStream_t stream)
{
    const float* x     = (const float*)d_in[0];
    const float* y     = (const float*)d_in[1];
    const float* Wxh   = (const float*)d_in[2];
    const float* Whh   = (const float*)d_in[3];
    const float* bh    = (const float*)d_in[4];
    const float* Wy    = (const float*)d_in[5];
    const float* by    = (const float*)d_in[6];
    const float* prior = (const float*)d_in[7];

    float* out      = (float*)d_out;
    float* corrects = out;
    float* latents  = out + (size_t)BB * TT;
    float* lossp    = out + (size_t)2 * BB * TT;

    // workspace layout (floats): hstart4 first for 16B alignment
    float*  ws       = (float*)d_ws;
    float4* hstart4  = (float4*)ws;                          // BB*NW float4 (8 MB)
    float2* AB2      = (float2*)(ws + (size_t)BB * NW * 4);  // BB*NW float2 (4 MB)
    float*  latstart = ws + (size_t)BB * NW * 6;             // BB*NW (2 MB)
    float*  partials = latstart + (size_t)BB * NW;           // 8192 floats

    const int thr = BB * NW;                                 // 524288 lanes each sweep

    bkt_sweep1<<<thr / 256, 256, 0, stream>>>(x, Wxh, Whh, bh, Wy, by, AB2, hstart4);
    bkt_mid<<<BB / 256, 256, 0, stream>>>(AB2, prior, latstart);
    bkt_sweep2<<<thr / 256, 256, 0, stream>>>(x, y, Wxh, Whh, bh, Wy, by,
                                              hstart4, latstart,
                                              corrects, latents, partials);
    bkt_loss<<<1, 256, 0, stream>>>(partials, thr / 64, lossp);
}

// Round 10
// 121.882 us; speedup vs baseline: 2.0478x; 1.2646x over previous
//
#include <hip/hip_runtime.h>

#define BB 8192
#define TT 2048
// sweep1: chunks of 64 steps, 16-step h warmup; emits 2x (h, A, B) at 32-step windows
#define NC1 32
#define CL1 64
#define WU  16
// sweep2: 32-step windows, 1 per lane; one wave = one row
#define NW  64   // windows per row
#define CL2 32
#define LST 33   // LDS stride per window (words): odd -> conflict-free b32 ops

__device__ __forceinline__ float sig2(float z) {
    return __builtin_amdgcn_rcpf(1.f + __builtin_amdgcn_exp2f(z));
}
__device__ __forceinline__ float sgpr(float v) {
    return __builtin_bit_cast(float, __builtin_amdgcn_readfirstlane(__builtin_bit_cast(int, v)));
}
__device__ __forceinline__ void ld16(float* d, const float* p) {
    *(float4*)(d)      = *(const float4*)(p);
    *(float4*)(d + 4)  = *(const float4*)(p + 4);
    *(float4*)(d + 8)  = *(const float4*)(p + 8);
    *(float4*)(d + 12) = *(const float4*)(p + 12);
}

#define LOAD_WHH()                                                                  \
    const float wh00=sgpr(Whh[0]*NL2E),  wh01=sgpr(Whh[1]*NL2E),                    \
                wh02=sgpr(Whh[2]*NL2E),  wh03=sgpr(Whh[3]*NL2E),                    \
                wh10=sgpr(Whh[4]*NL2E),  wh11=sgpr(Whh[5]*NL2E),                    \
                wh12=sgpr(Whh[6]*NL2E),  wh13=sgpr(Whh[7]*NL2E),                    \
                wh20=sgpr(Whh[8]*NL2E),  wh21=sgpr(Whh[9]*NL2E),                    \
                wh22=sgpr(Whh[10]*NL2E), wh23=sgpr(Whh[11]*NL2E),                   \
                wh30=sgpr(Whh[12]*NL2E), wh31=sgpr(Whh[13]*NL2E),                   \
                wh32=sgpr(Whh[14]*NL2E), wh33=sgpr(Whh[15]*NL2E);                   \
    const float wx0=sgpr(Wxh[0]*NL2E), wx1=sgpr(Wxh[1]*NL2E),                       \
                wx2=sgpr(Wxh[2]*NL2E), wx3=sgpr(Wxh[3]*NL2E);                       \
    const float bh0=sgpr(bh[0]*NL2E), bh1=sgpr(bh[1]*NL2E),                         \
                bh2=sgpr(bh[2]*NL2E), bh3=sgpr(bh[3]*NL2E);

#define HSTEP(xs)                                                                   \
    {                                                                               \
        float z0 = fmaf(h3,wh30,fmaf(h2,wh20,fmaf(h1,wh10,fmaf(h0,wh00,fmaf(xs,wx0,bh0))))); \
        float z1 = fmaf(h3,wh31,fmaf(h2,wh21,fmaf(h1,wh11,fmaf(h0,wh01,fmaf(xs,wx1,bh1))))); \
        float z2 = fmaf(h3,wh32,fmaf(h2,wh22,fmaf(h1,wh12,fmaf(h0,wh02,fmaf(xs,wx2,bh2))))); \
        float z3 = fmaf(h3,wh33,fmaf(h2,wh23,fmaf(h1,wh13,fmaf(h0,wh03,fmaf(xs,wx3,bh3))))); \
        h0 = sig2(z0); h1 = sig2(z1); h2 = sig2(z2); h3 = sig2(z3);                 \
    }
#define HSTEPx16(buf)                                                               \
    HSTEP(buf[0])  HSTEP(buf[1])  HSTEP(buf[2])  HSTEP(buf[3])                      \
    HSTEP(buf[4])  HSTEP(buf[5])  HSTEP(buf[6])  HSTEP(buf[7])                      \
    HSTEP(buf[8])  HSTEP(buf[9])  HSTEP(buf[10]) HSTEP(buf[11])                     \
    HSTEP(buf[12]) HSTEP(buf[13]) HSTEP(buf[14]) HSTEP(buf[15])

// ---- sweep 1: lane = (row b, 64-step chunk c1); 2 h-snapshots + 2 (A,B) windows ----
__global__ __launch_bounds__(256, 4) void bkt_sweep1(
    const float* __restrict__ x, const float* __restrict__ Wxh,
    const float* __restrict__ Whh, const float* __restrict__ bh,
    const float* __restrict__ Wy, const float* __restrict__ by,
    float2* __restrict__ AB2, float4* __restrict__ hstart4)
{
    const int tid = blockIdx.x * 256 + threadIdx.x;   // = b*32 + c1
    const int c1 = tid & (NC1 - 1);
    const int b  = tid >> 5;
    const float NL2E = -1.44269504088896340736f;

    LOAD_WHH();
    const float wl0=sgpr(Wy[0]*NL2E),  wl1=sgpr(Wy[4]*NL2E),
                wl2=sgpr(Wy[8]*NL2E),  wl3=sgpr(Wy[12]*NL2E);
    const float wf0=sgpr(Wy[1]*NL2E),  wf1=sgpr(Wy[5]*NL2E),
                wf2=sgpr(Wy[9]*NL2E),  wf3=sgpr(Wy[13]*NL2E);
    const float byl=sgpr(by[0]*NL2E), byf=sgpr(by[1]*NL2E);

    const float* xr = x + (size_t)b * TT;
    const int t0 = c1 * CL1;

    float xa[16], xn[16];
    ld16(xa, xr + (c1 ? t0 - WU : 0));       // warmup block
    ld16(xn, xr + t0);                       // window 0 first half

    float h0=0.f, h1=0.f, h2=0.f, h3=0.f;
    HSTEPx16(xa)
    if (c1 == 0) { h0 = h1 = h2 = h3 = 0.f; }   // exact start for first chunk

    float Aacc, Bacc;
#define S1(buf, s)                                                                  \
    {                                                                               \
        float zl = fmaf(h3,wl3,fmaf(h2,wl2,fmaf(h1,wl1,fmaf(h0,wl0,byl))));         \
        float zf = fmaf(h3,wf3,fmaf(h2,wf2,fmaf(h1,wf1,fmaf(h0,wf0,byf))));         \
        float pl = sig2(zl), pf = sig2(zf);                                         \
        float a = (1.f - pf) - pl;                                                  \
        Bacc = fmaf(a, Bacc, pl);                                                   \
        Aacc *= a;                                                                  \
        HSTEP(buf[s])                                                               \
    }
#define S1x16(buf)                                                                  \
    S1(buf,0)  S1(buf,1)  S1(buf,2)  S1(buf,3)  S1(buf,4)  S1(buf,5)  S1(buf,6)  S1(buf,7) \
    S1(buf,8)  S1(buf,9)  S1(buf,10) S1(buf,11) S1(buf,12) S1(buf,13) S1(buf,14) S1(buf,15)

    const float4 hs0 = make_float4(h0, h1, h2, h3);     // h entering window 2c1
    ld16(xa, xr + t0 + 16);
    Aacc = 1.f; Bacc = 0.f;
    S1x16(xn)                                           // t0 .. t0+15
    ld16(xn, xr + t0 + 32);
    S1x16(xa)                                           // t0+16 .. t0+31
    const float A0 = Aacc, B0 = Bacc;
    const float4 hs1 = make_float4(h0, h1, h2, h3);     // h entering window 2c1+1
    ld16(xa, xr + t0 + 48);
    Aacc = 1.f; Bacc = 0.f;
    S1x16(xn)                                           // t0+32 .. t0+47
    S1x16(xa)                                           // t0+48 .. t0+63
#undef S1x16
#undef S1

    float4* hp = hstart4 + (size_t)b * NW + 2 * c1;
    hp[0] = hs0; hp[1] = hs1;
    *(float4*)&AB2[(size_t)b * NW + 2 * c1] = make_float4(A0, B0, Aacc, Bacc);
}

// ---- sweep 2: lane = 32-step window; one wave = one row; in-wave affine scan ----
__global__ __launch_bounds__(256, 4) void bkt_sweep2(
    const float* __restrict__ x, const float* __restrict__ y,
    const float* __restrict__ Wxh, const float* __restrict__ Whh,
    const float* __restrict__ bh, const float* __restrict__ Wy,
    const float* __restrict__ by, const float* __restrict__ prior,
    const float4* __restrict__ hstart4, const float2* __restrict__ AB2,
    float* __restrict__ corrects, float* __restrict__ latents,
    float* __restrict__ partials)
{
    __shared__ float lds[4 * NW * LST];                // 33.8 KB: one slice per wave
    const int tid  = blockIdx.x * 256 + threadIdx.x;   // = b*64 + c
    const int lane = threadIdx.x & 63;                 // = window c
    const int b    = tid >> 6;                         // row (uniform per wave)
    float* wls = &lds[(threadIdx.x >> 6) * NW * LST];
    const int w33 = lane * LST;                        // this lane's LDS row
    const float NL2E = -1.44269504088896340736f;

    LOAD_WHH();
    const float wy00=sgpr(Wy[0]*NL2E),  wy01=sgpr(Wy[1]*NL2E),
                wy02=sgpr(Wy[2]*NL2E),  wy03=sgpr(Wy[3]*NL2E),
                wy10=sgpr(Wy[4]*NL2E),  wy11=sgpr(Wy[5]*NL2E),
                wy12=sgpr(Wy[6]*NL2E),  wy13=sgpr(Wy[7]*NL2E),
                wy20=sgpr(Wy[8]*NL2E),  wy21=sgpr(Wy[9]*NL2E),
                wy22=sgpr(Wy[10]*NL2E), wy23=sgpr(Wy[11]*NL2E),
                wy30=sgpr(Wy[12]*NL2E), wy31=sgpr(Wy[13]*NL2E),
                wy32=sgpr(Wy[14]*NL2E), wy33=sgpr(Wy[15]*NL2E);
    const float by0=sgpr(by[0]*NL2E), by1=sgpr(by[1]*NL2E),
                by2=sgpr(by[2]*NL2E), by3=sgpr(by[3]*NL2E);

    const int t0 = lane * CL2;
    const float* xr = x + (size_t)b * TT + t0;
    const float* yr = y + (size_t)b * TT + t0;
    float* crow = corrects + (size_t)b * TT;
    float* lrow = latents  + (size_t)b * TT;

    // ---- in-wave affine scan: lat entering window `lane` ----
    // inclusive scan of (A,B) maps (apply low lanes first), then exclusive shift
    const float2 ab = AB2[(size_t)b * NW + lane];
    float As = ab.x, Bs = ab.y;
#pragma unroll
    for (int off = 1; off < 64; off <<= 1) {
        float Au = __shfl_up(As, off);
        float Bu = __shfl_up(Bs, off);
        if (lane >= off) { Bs = fmaf(As, Bu, Bs); As *= Au; }
    }
    const float Ae = __shfl_up(As, 1);
    const float Be = __shfl_up(Bs, 1);
    const float pr = prior[0];
    float lat = (lane == 0) ? pr : fmaf(Ae, pr, Be);

    const float4 hv = hstart4[(size_t)b * NW + lane];
    float h0 = hv.x, h1 = hv.y, h2 = hv.z, h3 = hv.w;
    float lacc = 0.f;

    float xb[16], yb[16], lb[32];

    // stream correct -> LDS (ds_write_b32, stride-33 = conflict-free); latents in regs
#define S2(s, o)                                                                    \
    {                                                                               \
        float zl = fmaf(h3,wy30,fmaf(h2,wy20,fmaf(h1,wy10,fmaf(h0,wy00,by0))));     \
        float zf = fmaf(h3,wy31,fmaf(h2,wy21,fmaf(h1,wy11,fmaf(h0,wy01,by1))));     \
        float zg = fmaf(h3,wy32,fmaf(h2,wy22,fmaf(h1,wy12,fmaf(h0,wy02,by2))));     \
        float zs = fmaf(h3,wy33,fmaf(h2,wy23,fmaf(h1,wy13,fmaf(h0,wy03,by3))));     \
        float pl = sig2(zl), pf = sig2(zf), pg = sig2(zg), ps = sig2(zs);           \
        float correct = fmaf(lat, (1.f - ps) - pg, pg);                             \
        float nl      = fmaf(lat, (1.f - pf) - pl, pl);                             \
        float cc  = fminf(fmaxf(correct, 1e-7f), 1.f - 1e-7f);                      \
        float arg = fmaf(yb[s], fmaf(2.f, cc, -1.f), 1.f - cc);                     \
        lacc += __builtin_amdgcn_logf(arg);                                         \
        wls[w33 + (o) + (s)] = correct;                                             \
        lb[(o)+(s)] = nl; lat = nl;                                                 \
        HSTEP(xb[s])                                                                \
    }
#define S2x16(o)                                                                    \
    S2(0,o)  S2(1,o)  S2(2,o)  S2(3,o)  S2(4,o)  S2(5,o)  S2(6,o)  S2(7,o)          \
    S2(8,o)  S2(9,o)  S2(10,o) S2(11,o) S2(12,o) S2(13,o) S2(14,o) S2(15,o)

    ld16(xb, xr);      ld16(yb, yr);
    S2x16(0)
    ld16(xb, xr + 16); ld16(yb, yr + 16);
    S2x16(16)
#undef S2x16
#undef S2

    // ---- corrects: transposed readback; each global store instr = contiguous 1 KB ----
#pragma unroll
    for (int j = 0; j < 8; ++j) {
        const int base = (8 * j + (lane >> 3)) * LST + 4 * (lane & 7);
        float4 v = make_float4(wls[base], wls[base + 1], wls[base + 2], wls[base + 3]);
        *(float4*)(crow + j * 256 + 4 * lane) = v;
    }
    // ---- latents: dump regs to the same slice, then transposed readback ----
#pragma unroll
    for (int s = 0; s < 32; ++s) wls[w33 + s] = lb[s];
#pragma unroll
    for (int j = 0; j < 8; ++j) {
        const int base = (8 * j + (lane >> 3)) * LST + 4 * (lane & 7);
        float4 v = make_float4(wls[base], wls[base + 1], wls[base + 2], wls[base + 3]);
        *(float4*)(lrow + j * 256 + 4 * lane) = v;
    }

#pragma unroll
    for (int off = 32; off; off >>= 1) lacc += __shfl_down(lacc, off);
    if ((threadIdx.x & 63) == 0) partials[tid >> 6] = lacc;
}

__global__ __launch_bounds__(256) void bkt_loss(const float* __restrict__ partials, int n,
                                                float* __restrict__ out_loss)
{
    __shared__ double sd[4];
    double s = 0.0;
    for (int i = threadIdx.x; i < n; i += 256) s += (double)partials[i];
#pragma unroll
    for (int off = 32; off; off >>= 1) s += __shfl_down(s, off);
    if ((threadIdx.x & 63) == 0) sd[threadIdx.x >> 6] = s;
    __syncthreads();
    if (threadIdx.x == 0) {
        double t = sd[0] + sd[1] + sd[2] + sd[3];
        *out_loss = (float)(-t * 0.69314718055994530942 / ((double)BB * (double)TT));
    }
}

extern "C" void kernel_launch(void* const* d_in, const int* in_sizes, int n_in,
                              void* d_out, int out_size, void* d_ws, size_t ws_size,
                              hipStream_t stream)
{
    const float* x     = (const float*)d_in[0];
    const float* y     = (const float*)d_in[1];
    const float* Wxh   = (const float*)d_in[2];
    const float* Whh   = (const float*)d_in[3];
    const float* bh    = (const float*)d_in[4];
    const float* Wy    = (const float*)d_in[5];
    const float* by    = (const float*)d_in[6];
    const float* prior = (const float*)d_in[7];

    float* out      = (float*)d_out;
    float* corrects = out;
    float* latents  = out + (size_t)BB * TT;
    float* lossp    = out + (size_t)2 * BB * TT;

    // workspace layout (floats): hstart4 first for 16B alignment
    float*  ws       = (float*)d_ws;
    float4* hstart4  = (float4*)ws;                          // BB*NW float4 (8 MB)
    float2* AB2      = (float2*)(ws + (size_t)BB * NW * 4);  // BB*NW float2 (4 MB)
    float*  partials = ws + (size_t)BB * NW * 6;             // 8192 floats

    const int thr1 = BB * NC1;                               // 262144
    const int thr2 = BB * NW;                                // 524288

    bkt_sweep1<<<thr1 / 256, 256, 0, stream>>>(x, Wxh, Whh, bh, Wy, by, AB2, hstart4);
    bkt_sweep2<<<thr2 / 256, 256, 0, stream>>>(x, y, Wxh, Whh, bh, Wy, by, prior,
                                               hstart4, AB2,
                                               corrects, latents, partials);
    bkt_loss<<<1, 256, 0, stream>>>(partials, thr2 / 64, lossp);
}